// Round 9
// baseline (126.984 us; speedup 1.0000x reference)
//
#include <hip/hip_runtime.h>
#include <hip/hip_bf16.h>
#include <cstdint>
#include <cstddef>

#define B_ 8
#define C_ 64
#define CI 32
#define N_ 4096
#define LOG2E 1.44269504088896340736f

typedef __attribute__((ext_vector_type(8))) short bf16x8;
typedef __attribute__((ext_vector_type(4))) float f32x4;

static __device__ __forceinline__ ushort f2bf(float x) {
  union { float f; uint32_t u; } v; v.f = x;
  uint32_t r = v.u + 0x7FFFu + ((v.u >> 16) & 1u);
  return (ushort)(r >> 16);
}

static __device__ __forceinline__ uint32_t cvt_pk_bf16(float lo, float hi) {
  uint32_t r;
  asm("v_cvt_pk_bf16_f32 %0, %1, %2" : "=v"(r) : "v"(lo), "v"(hi));
  return r;
}

// -------- Kernel 1: 1x1-conv projections, W staged in LDS ------------------
// z=0: theta_t (B,N,CI) scaled by log2e; z=1: phi_t (B,N,CI); z=2: gmat (B,CI,N)
__global__ __launch_bounds__(256) void proj_kernel(
    const float* __restrict__ x,
    const float* __restrict__ Wg, const float* __restrict__ bg,
    const float* __restrict__ Wt, const float* __restrict__ bt,
    const float* __restrict__ Wp, const float* __restrict__ bp,
    ushort* __restrict__ theta_t, ushort* __restrict__ phi_t,
    ushort* __restrict__ gmat)
{
  __shared__ float WLt[C_ * CI];   // W transposed: [c][d], 8KB
  __shared__ float bL[CI];

  const int z = blockIdx.z;
  const float* W; const float* bias;
  if (z == 0)      { W = Wt; bias = bt; }
  else if (z == 1) { W = Wp; bias = bp; }
  else             { W = Wg; bias = bg; }

  const int t = threadIdx.x;
  #pragma unroll
  for (int k = 0; k < 8; ++k) {
    const int i = t + k * 256;            // i = d*C + c
    WLt[(i % C_) * CI + (i / C_)] = W[i];
  }
  if (t < CI) bL[t] = bias[t];
  __syncthreads();

  const int b = blockIdx.y;
  const int n = blockIdx.x * 64 + (t & 63);
  const int dq = t >> 6;                  // wave-uniform channel quarter
  const float* xb = x + ((size_t)b * C_) * N_ + n;

  float acc[8];
  #pragma unroll
  for (int i = 0; i < 8; ++i) acc[i] = bL[dq * 8 + i];

  #pragma unroll 8
  for (int c = 0; c < C_; ++c) {
    const float xv = xb[(size_t)c * N_];
    const float4 w0 = *(const float4*)&WLt[c * CI + dq * 8];
    const float4 w1 = *(const float4*)&WLt[c * CI + dq * 8 + 4];
    acc[0] = fmaf(w0.x, xv, acc[0]);
    acc[1] = fmaf(w0.y, xv, acc[1]);
    acc[2] = fmaf(w0.z, xv, acc[2]);
    acc[3] = fmaf(w0.w, xv, acc[3]);
    acc[4] = fmaf(w1.x, xv, acc[4]);
    acc[5] = fmaf(w1.y, xv, acc[5]);
    acc[6] = fmaf(w1.z, xv, acc[6]);
    acc[7] = fmaf(w1.w, xv, acc[7]);
  }

  if (z == 2) {
    #pragma unroll
    for (int i = 0; i < 8; ++i)
      gmat[((size_t)(b * CI) + dq * 8 + i) * N_ + n] = f2bf(acc[i]);
  } else {
    const float scale = (z == 0) ? LOG2E : 1.0f;
    uint32_t w[4];
    #pragma unroll
    for (int k = 0; k < 4; ++k)
      w[k] = (uint32_t)f2bf(acc[2 * k] * scale) |
             ((uint32_t)f2bf(acc[2 * k + 1] * scale) << 16);
    ushort* base = (z == 0) ? theta_t : phi_t;
    *(uint4*)(base + ((size_t)(b * N_) + n) * CI + dq * 8) =
        make_uint4(w[0], w[1], w[2], w[3]);
  }
}

// -------- Kernel 2: flash attention, one-deep pipelined PV -----------------
// Hazard-proof body: QK(s) | drain(prev writes) | read P(s-1) | softmax(s)
// (hides read) | drain(reads) | PV(s-1)+rescale(s-1) | write P(s).
// Reads only touch data whose writes are provably complete.
#define QKPV_BODY(S, DO_PREV)                                                 \
  {                                                                           \
    constexpr int sP = ((S) + 3) & 3;                                         \
    f32x4 f[4];                                                               \
    __builtin_amdgcn_s_setprio(1);                                            \
    _Pragma("unroll")                                                         \
    for (int mt = 0; mt < 4; ++mt)                                            \
      f[mt] = __builtin_amdgcn_mfma_f32_16x16x32_bf16(                        \
          kf[mt], qfrag[S], (f32x4){0.f, 0.f, 0.f, 0.f}, 0, 0, 0);            \
    __builtin_amdgcn_s_setprio(0);                                            \
    /* drain previous body's P-writes (issued one body ago -> ~free) */       \
    asm volatile("s_waitcnt lgkmcnt(0)" ::: "memory");                        \
    __builtin_amdgcn_sched_barrier(0);                                        \
    const bf16x8 pfA = *(const bf16x8*)prd[((S) + 1) & 1][0];                 \
    const bf16x8 pfB = *(const bf16x8*)prd[((S) + 1) & 1][1];                 \
    float pm = -1e30f;                                                        \
    float pv[4][4];                                                           \
    _Pragma("unroll")                                                         \
    for (int mt = 0; mt < 4; ++mt) {                                          \
      _Pragma("unroll")                                                       \
      for (int rr = 0; rr < 4; ++rr) {                                        \
        const float fv = f[mt][rr];                                           \
        pm = fmaxf(pm, fv);                                                   \
        pv[mt][rr] = __builtin_amdgcn_exp2f(fv - m_run[S]);                   \
      }                                                                       \
      l_lane[S] += (pv[mt][0] + pv[mt][1]) + (pv[mt][2] + pv[mt][3]);         \
    }                                                                         \
    uint2 wv[4];                                                              \
    _Pragma("unroll")                                                         \
    for (int mt = 0; mt < 4; ++mt) {                                          \
      wv[mt].x = cvt_pk_bf16(pv[mt][0], pv[mt][1]);                           \
      wv[mt].y = cvt_pk_bf16(pv[mt][2], pv[mt][3]);                           \
    }                                                                         \
    /* drain our P-reads (softmax above hid their latency) */                 \
    asm volatile("s_waitcnt lgkmcnt(0)" ::: "memory");                        \
    __builtin_amdgcn_sched_barrier(0);                                        \
    if (DO_PREV) {                                                            \
      __builtin_amdgcn_s_setprio(1);                                          \
      acc[sP][0] = __builtin_amdgcn_mfma_f32_16x16x32_bf16(                   \
          vf0[0], pfA, acc[sP][0], 0, 0, 0);                                  \
      acc[sP][1] = __builtin_amdgcn_mfma_f32_16x16x32_bf16(                   \
          vf1[0], pfA, acc[sP][1], 0, 0, 0);                                  \
      acc[sP][0] = __builtin_amdgcn_mfma_f32_16x16x32_bf16(                   \
          vf0[1], pfB, acc[sP][0], 0, 0, 0);                                  \
      acc[sP][1] = __builtin_amdgcn_mfma_f32_16x16x32_bf16(                   \
          vf1[1], pfB, acc[sP][1], 0, 0, 0);                                  \
      __builtin_amdgcn_s_setprio(0);                                          \
      if (__any(pm_pend > m_run[sP] + 8.f)) {                                 \
        float pmr = fmaxf(pm_pend, __shfl_xor(pm_pend, 16));                  \
        pmr = fmaxf(pmr, __shfl_xor(pmr, 32));                                \
        const float mnew = fmaxf(m_run[sP], pmr);                             \
        const float sc = __builtin_amdgcn_exp2f(m_run[sP] - mnew);            \
        m_run[sP] = mnew;                                                     \
        acc[sP][0] *= sc; acc[sP][1] *= sc; l_lane[sP] *= sc;                 \
      }                                                                       \
    }                                                                         \
    pm_pend = pm;                                                             \
    _Pragma("unroll")                                                         \
    for (int mt = 0; mt < 4; ++mt)                                            \
      *(uint2*)pw[(S) & 1][mt] = wv[mt];                                      \
    __builtin_amdgcn_sched_barrier(0);                                        \
  }

__global__ __launch_bounds__(512, 4) void attn_kernel(
    const ushort* __restrict__ theta_t,
    const ushort* __restrict__ phi_t,
    const ushort* __restrict__ gmat,
    const float* __restrict__ Ww, const float* __restrict__ bw,
    const float* __restrict__ x, float* __restrict__ out)
{
  __shared__ union {
    ushort pt[8][2][16 * 64];     // per-wave ping-pong P tiles (main loop)
    float  accS[4][32][64];       // merge acc slots (merge phase)
  } Sh;
  __shared__ float mlS[4][8][64]; // merge m/l slots
  __shared__ float WwL[C_ * CI];
  __shared__ float Yl[32 * 66];

  const int tid = threadIdx.x;
  const int lane = tid & 63;
  const int mh = tid >> 6;        // wave = m-eighth 0..7
  const int bid = blockIdx.x;
  const int b = bid & 7;          // batch -> XCD slot (K/V L2-resident)
  const int n0 = (bid >> 3) * 64;
  const int g4 = lane >> 4;
  const int c16 = lane & 15;
  const int sw = (c16 & 7) << 4;

  #pragma unroll
  for (int i = 0; i < 4; ++i) WwL[tid + i * 512] = Ww[tid + i * 512];

  bf16x8 qfrag[4];
  #pragma unroll
  for (int s = 0; s < 4; ++s)
    qfrag[s] = *(const bf16x8*)(theta_t +
        ((size_t)(b * N_ + n0 + s * 16 + c16)) * CI + g4 * 8);

  f32x4 acc[4][2];
  #pragma unroll
  for (int s = 0; s < 4; ++s) {
    acc[s][0] = (f32x4){0.f, 0.f, 0.f, 0.f};
    acc[s][1] = (f32x4){0.f, 0.f, 0.f, 0.f};
  }
  float m_run[4] = {0.f, 0.f, 0.f, 0.f};
  float l_lane[4] = {0.f, 0.f, 0.f, 0.f};
  float pm_pend = 0.f;

  const int mq0 = mh * 512;
  const ushort* kbase = phi_t + ((size_t)(b * N_ + mq0 + c16)) * CI + g4 * 8;
  const ushort* vb0 = gmat + ((size_t)(b * CI + c16)) * N_ + mq0 + g4 * 8;
  const ushort* vb1 = vb0 + (size_t)16 * N_;

  char* pw[2][4]; const char* prd[2][2];
  #pragma unroll
  for (int pb = 0; pb < 2; ++pb) {
    #pragma unroll
    for (int mt = 0; mt < 4; ++mt)
      pw[pb][mt] = (char*)Sh.pt[mh][pb] + ((c16 * 128 + mt * 32 + g4 * 8) ^ sw);
    #pragma unroll
    for (int ks = 0; ks < 2; ++ks)
      prd[pb][ks] = (const char*)Sh.pt[mh][pb] +
                    ((c16 * 128 + ks * 64 + g4 * 16) ^ sw);
  }

  bf16x8 kf[4], kfn[4], vf0[2], vf1[2];
  #pragma unroll
  for (int mt = 0; mt < 4; ++mt)
    kfn[mt] = *(const bf16x8*)(kbase + (size_t)(mt * 16) * CI);

  const int NT = 8;               // 512 rows / 64 per tile
  for (int t = 0; t < NT; ++t) {
    #pragma unroll
    for (int mt = 0; mt < 4; ++mt) kf[mt] = kfn[mt];
    const int tn = (t + 1 < NT) ? t + 1 : t;
    #pragma unroll
    for (int mt = 0; mt < 4; ++mt)
      kfn[mt] = *(const bf16x8*)(kbase + (size_t)(tn * 64 + mt * 16) * CI);

    QKPV_BODY(0, (t > 0))         // PV(t-1,3) uses vf of t-1 (not yet reloaded)

    #pragma unroll
    for (int ks = 0; ks < 2; ++ks) {
      vf0[ks] = *(const bf16x8*)(vb0 + t * 64 + ks * 32);
      vf1[ks] = *(const bf16x8*)(vb1 + t * 64 + ks * 32);
    }

    QKPV_BODY(1, true)
    QKPV_BODY(2, true)
    QKPV_BODY(3, true)
  }

  // epilogue: PV + rescale for (NT-1, 3); P(3) lives in buffer 1
  {
    asm volatile("s_waitcnt lgkmcnt(0)" ::: "memory");   // drain body-3 writes
    __builtin_amdgcn_sched_barrier(0);
    const bf16x8 pfA = *(const bf16x8*)prd[1][0];
    const bf16x8 pfB = *(const bf16x8*)prd[1][1];
    asm volatile("s_waitcnt lgkmcnt(0)" ::: "memory");   // drain reads
    __builtin_amdgcn_sched_barrier(0);
    acc[3][0] = __builtin_amdgcn_mfma_f32_16x16x32_bf16(vf0[0], pfA, acc[3][0], 0, 0, 0);
    acc[3][1] = __builtin_amdgcn_mfma_f32_16x16x32_bf16(vf1[0], pfA, acc[3][1], 0, 0, 0);
    acc[3][0] = __builtin_amdgcn_mfma_f32_16x16x32_bf16(vf0[1], pfB, acc[3][0], 0, 0, 0);
    acc[3][1] = __builtin_amdgcn_mfma_f32_16x16x32_bf16(vf1[1], pfB, acc[3][1], 0, 0, 0);
    if (__any(pm_pend > m_run[3] + 8.f)) {
      float pmr = fmaxf(pm_pend, __shfl_xor(pm_pend, 16));
      pmr = fmaxf(pmr, __shfl_xor(pmr, 32));
      const float mnew = fmaxf(m_run[3], pmr);
      const float sc = __builtin_amdgcn_exp2f(m_run[3] - mnew);
      m_run[3] = mnew;
      acc[3][0] *= sc; acc[3][1] *= sc; l_lane[3] *= sc;
    }
  }

  // total l per q-column: sum the 4 g4 partials
  #pragma unroll
  for (int s = 0; s < 4; ++s) {
    l_lane[s] += __shfl_xor(l_lane[s], 16);
    l_lane[s] += __shfl_xor(l_lane[s], 32);
  }

  // ---- split-m merge: max-aware flash combine, 3-round tree ----
  #pragma unroll
  for (int r = 4; r >= 1; r >>= 1) {
    __syncthreads();
    if (mh >= r && mh < 2 * r) {
      float* ad = &Sh.accS[mh - r][0][0] + lane;
      float* md = &mlS[mh - r][0][0] + lane;
      #pragma unroll
      for (int s = 0; s < 4; ++s) {
        #pragma unroll
        for (int rr = 0; rr < 4; ++rr) {
          ad[(s * 8 + rr) * 64]     = acc[s][0][rr];
          ad[(s * 8 + 4 + rr) * 64] = acc[s][1][rr];
        }
        md[s * 64]       = m_run[s];
        md[(4 + s) * 64] = l_lane[s];
      }
    }
    __syncthreads();
    if (mh < r) {
      const float* as_ = &Sh.accS[mh][0][0] + lane;
      const float* ms_ = &mlS[mh][0][0] + lane;
      #pragma unroll
      for (int s = 0; s < 4; ++s) {
        const float mb = ms_[s * 64];
        const float lb = ms_[(4 + s) * 64];
        const float mM = fmaxf(m_run[s], mb);
        const float ea = __builtin_amdgcn_exp2f(m_run[s] - mM);
        const float eb = __builtin_amdgcn_exp2f(mb - mM);
        #pragma unroll
        for (int rr = 0; rr < 4; ++rr) {
          acc[s][0][rr] = acc[s][0][rr] * ea + as_[(s * 8 + rr) * 64] * eb;
          acc[s][1][rr] = acc[s][1][rr] * ea + as_[(s * 8 + 4 + rr) * 64] * eb;
        }
        l_lane[s] = l_lane[s] * ea + lb * eb;
        m_run[s] = mM;
      }
    }
  }
  __syncthreads();

  if (mh == 0) {
    #pragma unroll
    for (int s = 0; s < 4; ++s) {
      const float inv = 1.0f / l_lane[s];
      const int q = s * 16 + c16;
      #pragma unroll
      for (int rr = 0; rr < 4; ++rr) {
        Yl[(g4 * 4 + rr) * 66 + q]      = acc[s][0][rr] * inv;
        Yl[(16 + g4 * 4 + rr) * 66 + q] = acc[s][1][rr] * inv;
      }
    }
  }
  __syncthreads();

  // ---- fused out-projection + residual: out = Ww @ y + bw + x ----
  const int nl = tid & 63;
  const int cg = tid >> 6;
  float oacc[8];
  #pragma unroll
  for (int i = 0; i < 8; ++i) oacc[i] = bw[cg * 8 + i];
  #pragma unroll
  for (int d = 0; d < CI; ++d) {
    const float yv = Yl[d * 66 + nl];
    #pragma unroll
    for (int i = 0; i < 8; ++i)
      oacc[i] = fmaf(WwL[(cg * 8 + i) * CI + d], yv, oacc[i]);
  }
  #pragma unroll
  for (int i = 0; i < 8; ++i) {
    const size_t idx = ((size_t)(b * C_ + cg * 8 + i)) * N_ + n0 + nl;
    out[idx] = oacc[i] + x[idx];
  }
}

extern "C" void kernel_launch(void* const* d_in, const int* in_sizes, int n_in,
                              void* d_out, int out_size, void* d_ws, size_t ws_size,
                              hipStream_t stream) {
  const float* x  = (const float*)d_in[0];
  const float* Wg = (const float*)d_in[1];
  const float* bg = (const float*)d_in[2];
  const float* Wt = (const float*)d_in[3];
  const float* bt = (const float*)d_in[4];
  const float* Wp = (const float*)d_in[5];
  const float* bp = (const float*)d_in[6];
  const float* Ww = (const float*)d_in[7];
  const float* bw = (const float*)d_in[8];
  float* out = (float*)d_out;

  char* ws = (char*)d_ws;
  ushort* theta_t = (ushort*)(ws);
  ushort* phi_t   = (ushort*)(ws + (size_t)2 * 1024 * 1024);
  ushort* gmat    = (ushort*)(ws + (size_t)4 * 1024 * 1024);

  proj_kernel<<<dim3(N_ / 64, B_, 3), 256, 0, stream>>>(
      x, Wg, bg, Wt, bt, Wp, bp, theta_t, phi_t, gmat);
  attn_kernel<<<dim3((N_ / 64) * B_), 512, 0, stream>>>(
      theta_t, phi_t, gmat, Ww, bw, x, out);
}

// Round 10
// 66.621 us; speedup vs baseline: 1.9061x; 1.9061x over previous
//
#include <hip/hip_runtime.h>
#include <hip/hip_bf16.h>
#include <cstdint>
#include <cstddef>

#define B_ 8
#define C_ 64
#define CI 32
#define N_ 4096
#define LOG2E 1.44269504088896340736f

typedef __attribute__((ext_vector_type(8))) short bf16x8;
typedef __attribute__((ext_vector_type(4))) float f32x4;

static __device__ __forceinline__ ushort f2bf(float x) {
  union { float f; uint32_t u; } v; v.f = x;
  uint32_t r = v.u + 0x7FFFu + ((v.u >> 16) & 1u);
  return (ushort)(r >> 16);
}

static __device__ __forceinline__ uint32_t cvt_pk_bf16(float lo, float hi) {
  uint32_t r;
  asm("v_cvt_pk_bf16_f32 %0, %1, %2" : "=v"(r) : "v"(lo), "v"(hi));
  return r;
}

// -------- Kernel 1: 1x1-conv projections, W staged in LDS (r9-proven) ------
// z=0: theta_t (B,N,CI) scaled by log2e; z=1: phi_t (B,N,CI); z=2: gmat (B,CI,N)
__global__ __launch_bounds__(256) void proj_kernel(
    const float* __restrict__ x,
    const float* __restrict__ Wg, const float* __restrict__ bg,
    const float* __restrict__ Wt, const float* __restrict__ bt,
    const float* __restrict__ Wp, const float* __restrict__ bp,
    ushort* __restrict__ theta_t, ushort* __restrict__ phi_t,
    ushort* __restrict__ gmat)
{
  __shared__ float WLt[C_ * CI];   // W transposed: [c][d], 8KB
  __shared__ float bL[CI];

  const int z = blockIdx.z;
  const float* W; const float* bias;
  if (z == 0)      { W = Wt; bias = bt; }
  else if (z == 1) { W = Wp; bias = bp; }
  else             { W = Wg; bias = bg; }

  const int t = threadIdx.x;
  #pragma unroll
  for (int k = 0; k < 8; ++k) {
    const int i = t + k * 256;            // i = d*C + c
    WLt[(i % C_) * CI + (i / C_)] = W[i];
  }
  if (t < CI) bL[t] = bias[t];
  __syncthreads();

  const int b = blockIdx.y;
  const int n = blockIdx.x * 64 + (t & 63);
  const int dq = t >> 6;                  // wave-uniform channel quarter
  const float* xb = x + ((size_t)b * C_) * N_ + n;

  float acc[8];
  #pragma unroll
  for (int i = 0; i < 8; ++i) acc[i] = bL[dq * 8 + i];

  #pragma unroll 8
  for (int c = 0; c < C_; ++c) {
    const float xv = xb[(size_t)c * N_];
    const float4 w0 = *(const float4*)&WLt[c * CI + dq * 8];
    const float4 w1 = *(const float4*)&WLt[c * CI + dq * 8 + 4];
    acc[0] = fmaf(w0.x, xv, acc[0]);
    acc[1] = fmaf(w0.y, xv, acc[1]);
    acc[2] = fmaf(w0.z, xv, acc[2]);
    acc[3] = fmaf(w0.w, xv, acc[3]);
    acc[4] = fmaf(w1.x, xv, acc[4]);
    acc[5] = fmaf(w1.y, xv, acc[5]);
    acc[6] = fmaf(w1.z, xv, acc[6]);
    acc[7] = fmaf(w1.w, xv, acc[7]);
  }

  if (z == 2) {
    #pragma unroll
    for (int i = 0; i < 8; ++i)
      gmat[((size_t)(b * CI) + dq * 8 + i) * N_ + n] = f2bf(acc[i]);
  } else {
    const float scale = (z == 0) ? LOG2E : 1.0f;
    uint32_t w[4];
    #pragma unroll
    for (int k = 0; k < 4; ++k)
      w[k] = (uint32_t)f2bf(acc[2 * k] * scale) |
             ((uint32_t)f2bf(acc[2 * k + 1] * scale) << 16);
    ushort* base = (z == 0) ? theta_t : phi_t;
    *(uint4*)(base + ((size_t)(b * N_) + n) * CI + dq * 8) =
        make_uint4(w[0], w[1], w[2], w[3]);
  }
}

// -------- Kernel 2: flash attention, pair-batched drains -------------------
// r7 per-accumulator numerics exactly; per t: {QK+sm+wr}(s), {QK+sm+wr}(s+1),
// ONE drain, reads, PV(s), PV(s+1), rescale(s), rescale(s+1).

// QK + stale-max softmax + P-write for sub-tile S; records pm into PMVAR.
#define QKSM(S, PMVAR)                                                        \
  {                                                                           \
    f32x4 f[4];                                                               \
    __builtin_amdgcn_s_setprio(1);                                            \
    _Pragma("unroll")                                                         \
    for (int mt = 0; mt < 4; ++mt)                                            \
      f[mt] = __builtin_amdgcn_mfma_f32_16x16x32_bf16(                        \
          kf[mt], qfrag[S], (f32x4){0.f, 0.f, 0.f, 0.f}, 0, 0, 0);            \
    __builtin_amdgcn_s_setprio(0);                                            \
    float pm = -1e30f;                                                        \
    float pv[4][4];                                                           \
    _Pragma("unroll")                                                         \
    for (int mt = 0; mt < 4; ++mt) {                                          \
      _Pragma("unroll")                                                       \
      for (int rr = 0; rr < 4; ++rr) {                                        \
        const float fv = f[mt][rr];                                           \
        pm = fmaxf(pm, fv);                                                   \
        pv[mt][rr] = __builtin_amdgcn_exp2f(fv - m_run[S]);                   \
      }                                                                       \
      l_lane[S] += (pv[mt][0] + pv[mt][1]) + (pv[mt][2] + pv[mt][3]);         \
    }                                                                         \
    _Pragma("unroll")                                                         \
    for (int mt = 0; mt < 4; ++mt) {                                          \
      uint2 wv;                                                               \
      wv.x = cvt_pk_bf16(pv[mt][0], pv[mt][1]);                               \
      wv.y = cvt_pk_bf16(pv[mt][2], pv[mt][3]);                               \
      *(uint2*)pw[(S) & 1][mt] = wv;                                          \
    }                                                                         \
    PMVAR = pm;                                                               \
  }

#define PV4(S, PA, PB)                                                        \
  acc[S][0] = __builtin_amdgcn_mfma_f32_16x16x32_bf16(                        \
      vf0[0], PA, acc[S][0], 0, 0, 0);                                        \
  acc[S][1] = __builtin_amdgcn_mfma_f32_16x16x32_bf16(                        \
      vf1[0], PA, acc[S][1], 0, 0, 0);                                        \
  acc[S][0] = __builtin_amdgcn_mfma_f32_16x16x32_bf16(                        \
      vf0[1], PB, acc[S][0], 0, 0, 0);                                        \
  acc[S][1] = __builtin_amdgcn_mfma_f32_16x16x32_bf16(                        \
      vf1[1], PB, acc[S][1], 0, 0, 0);

#define RESC(S, PMVAR)                                                        \
  if (__any(PMVAR > m_run[S] + 8.f)) {                                        \
    float pmr = fmaxf(PMVAR, __shfl_xor(PMVAR, 16));                          \
    pmr = fmaxf(pmr, __shfl_xor(pmr, 32));                                    \
    const float mnew = fmaxf(m_run[S], pmr);                                  \
    const float sc = __builtin_amdgcn_exp2f(m_run[S] - mnew);                 \
    m_run[S] = mnew;                                                          \
    acc[S][0] *= sc; acc[S][1] *= sc; l_lane[S] *= sc;                        \
  }

#define PAIR(S0, S1)                                                          \
  {                                                                           \
    float pmA, pmB;                                                           \
    QKSM(S0, pmA)                                                             \
    QKSM(S1, pmB)                                                             \
    asm volatile("s_waitcnt lgkmcnt(0)" ::: "memory");                        \
    __builtin_amdgcn_sched_barrier(0);                                        \
    const bf16x8 p0A = *(const bf16x8*)prd[(S0) & 1][0];                      \
    const bf16x8 p0B = *(const bf16x8*)prd[(S0) & 1][1];                      \
    const bf16x8 p1A = *(const bf16x8*)prd[(S1) & 1][0];                      \
    const bf16x8 p1B = *(const bf16x8*)prd[(S1) & 1][1];                      \
    __builtin_amdgcn_s_setprio(1);                                            \
    PV4(S0, p0A, p0B)                                                         \
    PV4(S1, p1A, p1B)                                                         \
    __builtin_amdgcn_s_setprio(0);                                            \
    RESC(S0, pmA)                                                             \
    RESC(S1, pmB)                                                             \
    __builtin_amdgcn_sched_barrier(0);                                        \
  }

__global__ __launch_bounds__(512, 2) void attn_kernel(
    const ushort* __restrict__ theta_t,
    const ushort* __restrict__ phi_t,
    const ushort* __restrict__ gmat,
    const float* __restrict__ Ww, const float* __restrict__ bw,
    const float* __restrict__ x, float* __restrict__ out)
{
  __shared__ union {
    ushort pt[8][2][16 * 64];     // per-wave ping-pong P tiles (main loop)
    float  accS[4][32][64];       // merge acc slots (merge phase)
  } Sh;
  __shared__ float mlS[4][8][64]; // merge m/l slots
  __shared__ float WwL[C_ * CI];
  __shared__ float Yl[32 * 66];

  const int tid = threadIdx.x;
  const int lane = tid & 63;
  const int mh = tid >> 6;        // wave = m-eighth 0..7
  const int bid = blockIdx.x;
  const int b = bid & 7;          // batch -> XCD slot (K/V L2-resident)
  const int n0 = (bid >> 3) * 64;
  const int g4 = lane >> 4;
  const int c16 = lane & 15;
  const int sw = (c16 & 7) << 4;

  #pragma unroll
  for (int i = 0; i < 4; ++i) WwL[tid + i * 512] = Ww[tid + i * 512];

  bf16x8 qfrag[4];
  #pragma unroll
  for (int s = 0; s < 4; ++s)
    qfrag[s] = *(const bf16x8*)(theta_t +
        ((size_t)(b * N_ + n0 + s * 16 + c16)) * CI + g4 * 8);

  f32x4 acc[4][2];
  #pragma unroll
  for (int s = 0; s < 4; ++s) {
    acc[s][0] = (f32x4){0.f, 0.f, 0.f, 0.f};
    acc[s][1] = (f32x4){0.f, 0.f, 0.f, 0.f};
  }
  float m_run[4] = {0.f, 0.f, 0.f, 0.f};
  float l_lane[4] = {0.f, 0.f, 0.f, 0.f};

  const int mq0 = mh * 512;
  const ushort* kbase = phi_t + ((size_t)(b * N_ + mq0 + c16)) * CI + g4 * 8;
  const ushort* vb0 = gmat + ((size_t)(b * CI + c16)) * N_ + mq0 + g4 * 8;
  const ushort* vb1 = vb0 + (size_t)16 * N_;

  char* pw[2][4]; const char* prd[2][2];
  #pragma unroll
  for (int pb = 0; pb < 2; ++pb) {
    #pragma unroll
    for (int mt = 0; mt < 4; ++mt)
      pw[pb][mt] = (char*)Sh.pt[mh][pb] + ((c16 * 128 + mt * 32 + g4 * 8) ^ sw);
    #pragma unroll
    for (int ks = 0; ks < 2; ++ks)
      prd[pb][ks] = (const char*)Sh.pt[mh][pb] +
                    ((c16 * 128 + ks * 64 + g4 * 16) ^ sw);
  }

  bf16x8 kf[4], kfn[4], vf0[2], vf1[2];
  #pragma unroll
  for (int mt = 0; mt < 4; ++mt)
    kfn[mt] = *(const bf16x8*)(kbase + (size_t)(mt * 16) * CI);

  const int NT = 8;               // 512 rows / 64 per tile
  for (int t = 0; t < NT; ++t) {
    #pragma unroll
    for (int mt = 0; mt < 4; ++mt) kf[mt] = kfn[mt];
    const int tn = (t + 1 < NT) ? t + 1 : t;
    #pragma unroll
    for (int mt = 0; mt < 4; ++mt)
      kfn[mt] = *(const bf16x8*)(kbase + (size_t)(tn * 64 + mt * 16) * CI);
    #pragma unroll
    for (int ks = 0; ks < 2; ++ks) {
      vf0[ks] = *(const bf16x8*)(vb0 + t * 64 + ks * 32);
      vf1[ks] = *(const bf16x8*)(vb1 + t * 64 + ks * 32);
    }

    PAIR(0, 1)
    PAIR(2, 3)
  }

  // total l per q-column: sum the 4 g4 partials
  #pragma unroll
  for (int s = 0; s < 4; ++s) {
    l_lane[s] += __shfl_xor(l_lane[s], 16);
    l_lane[s] += __shfl_xor(l_lane[s], 32);
  }

  // ---- split-m merge: max-aware flash combine, 3-round tree ----
  #pragma unroll
  for (int r = 4; r >= 1; r >>= 1) {
    __syncthreads();
    if (mh >= r && mh < 2 * r) {
      float* ad = &Sh.accS[mh - r][0][0] + lane;
      float* md = &mlS[mh - r][0][0] + lane;
      #pragma unroll
      for (int s = 0; s < 4; ++s) {
        #pragma unroll
        for (int rr = 0; rr < 4; ++rr) {
          ad[(s * 8 + rr) * 64]     = acc[s][0][rr];
          ad[(s * 8 + 4 + rr) * 64] = acc[s][1][rr];
        }
        md[s * 64]       = m_run[s];
        md[(4 + s) * 64] = l_lane[s];
      }
    }
    __syncthreads();
    if (mh < r) {
      const float* as_ = &Sh.accS[mh][0][0] + lane;
      const float* ms_ = &mlS[mh][0][0] + lane;
      #pragma unroll
      for (int s = 0; s < 4; ++s) {
        const float mb = ms_[s * 64];
        const float lb = ms_[(4 + s) * 64];
        const float mM = fmaxf(m_run[s], mb);
        const float ea = __builtin_amdgcn_exp2f(m_run[s] - mM);
        const float eb = __builtin_amdgcn_exp2f(mb - mM);
        #pragma unroll
        for (int rr = 0; rr < 4; ++rr) {
          acc[s][0][rr] = acc[s][0][rr] * ea + as_[(s * 8 + rr) * 64] * eb;
          acc[s][1][rr] = acc[s][1][rr] * ea + as_[(s * 8 + 4 + rr) * 64] * eb;
        }
        l_lane[s] = l_lane[s] * ea + lb * eb;
        m_run[s] = mM;
      }
    }
  }
  __syncthreads();

  if (mh == 0) {
    #pragma unroll
    for (int s = 0; s < 4; ++s) {
      const float inv = 1.0f / l_lane[s];
      const int q = s * 16 + c16;
      #pragma unroll
      for (int rr = 0; rr < 4; ++rr) {
        Yl[(g4 * 4 + rr) * 66 + q]      = acc[s][0][rr] * inv;
        Yl[(16 + g4 * 4 + rr) * 66 + q] = acc[s][1][rr] * inv;
      }
    }
  }
  __syncthreads();

  // ---- fused out-projection + residual: out = Ww @ y + bw + x ----
  const int nl = tid & 63;
  const int cg = tid >> 6;
  float oacc[8];
  #pragma unroll
  for (int i = 0; i < 8; ++i) oacc[i] = bw[cg * 8 + i];
  #pragma unroll
  for (int d = 0; d < CI; ++d) {
    const float yv = Yl[d * 66 + nl];
    #pragma unroll
    for (int i = 0; i < 8; ++i)
      oacc[i] = fmaf(WwL[(cg * 8 + i) * CI + d], yv, oacc[i]);
  }
  #pragma unroll
  for (int i = 0; i < 8; ++i) {
    const size_t idx = ((size_t)(b * C_ + cg * 8 + i)) * N_ + n0 + nl;
    out[idx] = oacc[i] + x[idx];
  }
}

extern "C" void kernel_launch(void* const* d_in, const int* in_sizes, int n_in,
                              void* d_out, int out_size, void* d_ws, size_t ws_size,
                              hipStream_t stream) {
  const float* x  = (const float*)d_in[0];
  const float* Wg = (const float*)d_in[1];
  const float* bg = (const float*)d_in[2];
  const float* Wt = (const float*)d_in[3];
  const float* bt = (const float*)d_in[4];
  const float* Wp = (const float*)d_in[5];
  const float* bp = (const float*)d_in[6];
  const float* Ww = (const float*)d_in[7];
  const float* bw = (const float*)d_in[8];
  float* out = (float*)d_out;

  char* ws = (char*)d_ws;
  ushort* theta_t = (ushort*)(ws);
  ushort* phi_t   = (ushort*)(ws + (size_t)2 * 1024 * 1024);
  ushort* gmat    = (ushort*)(ws + (size_t)4 * 1024 * 1024);

  proj_kernel<<<dim3(N_ / 64, B_, 3), 256, 0, stream>>>(
      x, Wg, bg, Wt, bt, Wp, bp, theta_t, phi_t, gmat);
  attn_kernel<<<dim3((N_ / 64) * B_), 512, 0, stream>>>(
      theta_t, phi_t, gmat, Ww, bw, x, out);
}

// Round 11
// 60.356 us; speedup vs baseline: 2.1039x; 1.1038x over previous
//
#include <hip/hip_runtime.h>
#include <hip/hip_bf16.h>
#include <cstdint>
#include <cstddef>

#define B_ 8
#define C_ 64
#define CI 32
#define N_ 4096
#define LOG2E 1.44269504088896340736f

typedef __attribute__((ext_vector_type(8))) short bf16x8;
typedef __attribute__((ext_vector_type(4))) float f32x4;

static __device__ __forceinline__ ushort f2bf(float x) {
  union { float f; uint32_t u; } v; v.f = x;
  uint32_t r = v.u + 0x7FFFu + ((v.u >> 16) & 1u);
  return (ushort)(r >> 16);
}

static __device__ __forceinline__ uint32_t cvt_pk_bf16(float lo, float hi) {
  uint32_t r;
  asm("v_cvt_pk_bf16_f32 %0, %1, %2" : "=v"(r) : "v"(lo), "v"(hi));
  return r;
}

// -------- Kernel 1: 1x1-conv projections, W staged in LDS (r9-proven) ------
// z=0: theta_t (B,N,CI) scaled by log2e; z=1: phi_t (B,N,CI); z=2: gmat (B,CI,N)
__global__ __launch_bounds__(256) void proj_kernel(
    const float* __restrict__ x,
    const float* __restrict__ Wg, const float* __restrict__ bg,
    const float* __restrict__ Wt, const float* __restrict__ bt,
    const float* __restrict__ Wp, const float* __restrict__ bp,
    ushort* __restrict__ theta_t, ushort* __restrict__ phi_t,
    ushort* __restrict__ gmat)
{
  __shared__ float WLt[C_ * CI];   // W transposed: [c][d], 8KB
  __shared__ float bL[CI];

  const int z = blockIdx.z;
  const float* W; const float* bias;
  if (z == 0)      { W = Wt; bias = bt; }
  else if (z == 1) { W = Wp; bias = bp; }
  else             { W = Wg; bias = bg; }

  const int t = threadIdx.x;
  #pragma unroll
  for (int k = 0; k < 8; ++k) {
    const int i = t + k * 256;            // i = d*C + c
    WLt[(i % C_) * CI + (i / C_)] = W[i];
  }
  if (t < CI) bL[t] = bias[t];
  __syncthreads();

  const int b = blockIdx.y;
  const int n = blockIdx.x * 64 + (t & 63);
  const int dq = t >> 6;                  // wave-uniform channel quarter
  const float* xb = x + ((size_t)b * C_) * N_ + n;

  float acc[8];
  #pragma unroll
  for (int i = 0; i < 8; ++i) acc[i] = bL[dq * 8 + i];

  #pragma unroll 8
  for (int c = 0; c < C_; ++c) {
    const float xv = xb[(size_t)c * N_];
    const float4 w0 = *(const float4*)&WLt[c * CI + dq * 8];
    const float4 w1 = *(const float4*)&WLt[c * CI + dq * 8 + 4];
    acc[0] = fmaf(w0.x, xv, acc[0]);
    acc[1] = fmaf(w0.y, xv, acc[1]);
    acc[2] = fmaf(w0.z, xv, acc[2]);
    acc[3] = fmaf(w0.w, xv, acc[3]);
    acc[4] = fmaf(w1.x, xv, acc[4]);
    acc[5] = fmaf(w1.y, xv, acc[5]);
    acc[6] = fmaf(w1.z, xv, acc[6]);
    acc[7] = fmaf(w1.w, xv, acc[7]);
  }

  if (z == 2) {
    #pragma unroll
    for (int i = 0; i < 8; ++i)
      gmat[((size_t)(b * CI) + dq * 8 + i) * N_ + n] = f2bf(acc[i]);
  } else {
    const float scale = (z == 0) ? LOG2E : 1.0f;
    uint32_t w[4];
    #pragma unroll
    for (int k = 0; k < 4; ++k)
      w[k] = (uint32_t)f2bf(acc[2 * k] * scale) |
             ((uint32_t)f2bf(acc[2 * k + 1] * scale) << 16);
    ushort* base = (z == 0) ? theta_t : phi_t;
    *(uint4*)(base + ((size_t)(b * N_) + n) * CI + dq * 8) =
        make_uint4(w[0], w[1], w[2], w[3]);
  }
}

// -------- Kernel 2: flash attention (r7 structure, lean softmax) -----------
// 8 waves = 8 m-eighths, q=64/wave. Per s: QK (C-init = -m, sub in matrix
// pipe) | exp2+l | P write | drain | PV | l-threshold rescale (rare, exact
// power-of-2). No fmax tree, no pm relay.
__global__ __launch_bounds__(512, 2) void attn_kernel(
    const ushort* __restrict__ theta_t,
    const ushort* __restrict__ phi_t,
    const ushort* __restrict__ gmat,
    const float* __restrict__ Ww, const float* __restrict__ bw,
    const float* __restrict__ x, float* __restrict__ out)
{
  __shared__ union {
    ushort pt[8][2][16 * 64];     // per-wave ping-pong P tiles (main loop)
    float  accS[4][32][64];       // merge acc slots (merge phase)
  } Sh;
  __shared__ float mlS[4][8][64]; // merge m/l slots
  __shared__ float WwL[C_ * CI];
  __shared__ float Yl[32 * 66];

  const int tid = threadIdx.x;
  const int lane = tid & 63;
  const int mh = tid >> 6;        // wave = m-eighth 0..7
  const int bid = blockIdx.x;
  const int b = bid & 7;          // batch -> XCD slot (K/V L2-resident)
  const int n0 = (bid >> 3) * 64;
  const int g4 = lane >> 4;
  const int c16 = lane & 15;
  const int sw = (c16 & 7) << 4;

  #pragma unroll
  for (int i = 0; i < 4; ++i) WwL[tid + i * 512] = Ww[tid + i * 512];

  bf16x8 qfrag[4];
  #pragma unroll
  for (int s = 0; s < 4; ++s)
    qfrag[s] = *(const bf16x8*)(theta_t +
        ((size_t)(b * N_ + n0 + s * 16 + c16)) * CI + g4 * 8);

  f32x4 acc[4][2];
  f32x4 cinit[4];                 // = splat(-m_run[s]); lives in regs
  #pragma unroll
  for (int s = 0; s < 4; ++s) {
    acc[s][0] = (f32x4){0.f, 0.f, 0.f, 0.f};
    acc[s][1] = (f32x4){0.f, 0.f, 0.f, 0.f};
    cinit[s]  = (f32x4){0.f, 0.f, 0.f, 0.f};
  }
  float l_lane[4] = {0.f, 0.f, 0.f, 0.f};

  const int mq0 = mh * 512;
  const ushort* kbase = phi_t + ((size_t)(b * N_ + mq0 + c16)) * CI + g4 * 8;
  const ushort* vb0 = gmat + ((size_t)(b * CI + c16)) * N_ + mq0 + g4 * 8;
  const ushort* vb1 = vb0 + (size_t)16 * N_;

  char* pw[2][4]; const char* prd[2][2];
  #pragma unroll
  for (int pb = 0; pb < 2; ++pb) {
    #pragma unroll
    for (int mt = 0; mt < 4; ++mt)
      pw[pb][mt] = (char*)Sh.pt[mh][pb] + ((c16 * 128 + mt * 32 + g4 * 8) ^ sw);
    #pragma unroll
    for (int ks = 0; ks < 2; ++ks)
      prd[pb][ks] = (const char*)Sh.pt[mh][pb] +
                    ((c16 * 128 + ks * 64 + g4 * 16) ^ sw);
  }

  bf16x8 kf[4], kfn[4], vf0[2], vf1[2];
  #pragma unroll
  for (int mt = 0; mt < 4; ++mt)
    kfn[mt] = *(const bf16x8*)(kbase + (size_t)(mt * 16) * CI);

  const int NT = 8;               // 512 rows / 64 per tile
  for (int t = 0; t < NT; ++t) {
    #pragma unroll
    for (int mt = 0; mt < 4; ++mt) kf[mt] = kfn[mt];
    const int tn = (t + 1 < NT) ? t + 1 : t;
    #pragma unroll
    for (int mt = 0; mt < 4; ++mt)
      kfn[mt] = *(const bf16x8*)(kbase + (size_t)(tn * 64 + mt * 16) * CI);
    #pragma unroll
    for (int ks = 0; ks < 2; ++ks) {
      vf0[ks] = *(const bf16x8*)(vb0 + t * 64 + ks * 32);
      vf1[ks] = *(const bf16x8*)(vb1 + t * 64 + ks * 32);
    }

    #pragma unroll
    for (int s = 0; s < 4; ++s) {
      const int pb = s & 1;
      f32x4 f[4];
      __builtin_amdgcn_s_setprio(1);
      #pragma unroll
      for (int mt = 0; mt < 4; ++mt)
        f[mt] = __builtin_amdgcn_mfma_f32_16x16x32_bf16(
            kf[mt], qfrag[s], cinit[s], 0, 0, 0);   // f = K.Q - m (free sub)
      __builtin_amdgcn_s_setprio(0);

      // p = exp2(f); l accumulates; no fmax tree (l-threshold guards range)
      float pv[4][4];
      #pragma unroll
      for (int mt = 0; mt < 4; ++mt) {
        #pragma unroll
        for (int rr = 0; rr < 4; ++rr)
          pv[mt][rr] = __builtin_amdgcn_exp2f(f[mt][rr]);
        l_lane[s] += (pv[mt][0] + pv[mt][1]) + (pv[mt][2] + pv[mt][3]);
      }
      #pragma unroll
      for (int mt = 0; mt < 4; ++mt) {
        uint2 wv;
        wv.x = cvt_pk_bf16(pv[mt][0], pv[mt][1]);
        wv.y = cvt_pk_bf16(pv[mt][2], pv[mt][3]);
        *(uint2*)pw[pb][mt] = wv;
      }
      // pin write->read order (compiler can't relate XOR'd char* aliases)
      asm volatile("s_waitcnt lgkmcnt(0)" ::: "memory");
      __builtin_amdgcn_sched_barrier(0);

      __builtin_amdgcn_s_setprio(1);
      #pragma unroll
      for (int ks = 0; ks < 2; ++ks) {
        const bf16x8 pfrag = *(const bf16x8*)prd[pb][ks];
        acc[s][0] = __builtin_amdgcn_mfma_f32_16x16x32_bf16(
            vf0[ks], pfrag, acc[s][0], 0, 0, 0);
        acc[s][1] = __builtin_amdgcn_mfma_f32_16x16x32_bf16(
            vf1[ks], pfrag, acc[s][1], 0, 0, 0);
      }
      __builtin_amdgcn_s_setprio(0);

      // l-threshold rescale: rare, exact power of 2; keeps l,p,acc in range.
      // Worst case between checks: l <= 2^59 << fp32 max; p <= 2^55 fits bf16.
      if (__any(l_lane[s] > 0x1p40f)) {
        const float sc = 0x1p-64f;
        acc[s][0] *= sc; acc[s][1] *= sc; l_lane[s] *= sc;
        #pragma unroll
        for (int rr = 0; rr < 4; ++rr) cinit[s][rr] -= 64.f;
      }
    }
  }

  // total l per q-column: sum the 4 g4 partials
  float m_run[4];
  #pragma unroll
  for (int s = 0; s < 4; ++s) {
    l_lane[s] += __shfl_xor(l_lane[s], 16);
    l_lane[s] += __shfl_xor(l_lane[s], 32);
    m_run[s] = -cinit[s][0];
  }

  // ---- split-m merge: max-aware flash combine, 3-round tree (r7-proven) ----
  #pragma unroll
  for (int r = 4; r >= 1; r >>= 1) {
    __syncthreads();
    if (mh >= r && mh < 2 * r) {
      float* ad = &Sh.accS[mh - r][0][0] + lane;
      float* md = &mlS[mh - r][0][0] + lane;
      #pragma unroll
      for (int s = 0; s < 4; ++s) {
        #pragma unroll
        for (int rr = 0; rr < 4; ++rr) {
          ad[(s * 8 + rr) * 64]     = acc[s][0][rr];
          ad[(s * 8 + 4 + rr) * 64] = acc[s][1][rr];
        }
        md[s * 64]       = m_run[s];
        md[(4 + s) * 64] = l_lane[s];
      }
    }
    __syncthreads();
    if (mh < r) {
      const float* as_ = &Sh.accS[mh][0][0] + lane;
      const float* ms_ = &mlS[mh][0][0] + lane;
      #pragma unroll
      for (int s = 0; s < 4; ++s) {
        const float mb = ms_[s * 64];
        const float lb = ms_[(4 + s) * 64];
        const float mM = fmaxf(m_run[s], mb);
        const float ea = __builtin_amdgcn_exp2f(m_run[s] - mM);
        const float eb = __builtin_amdgcn_exp2f(mb - mM);
        #pragma unroll
        for (int rr = 0; rr < 4; ++rr) {
          acc[s][0][rr] = acc[s][0][rr] * ea + as_[(s * 8 + rr) * 64] * eb;
          acc[s][1][rr] = acc[s][1][rr] * ea + as_[(s * 8 + 4 + rr) * 64] * eb;
        }
        l_lane[s] = l_lane[s] * ea + lb * eb;
        m_run[s] = mM;
      }
    }
  }
  __syncthreads();

  if (mh == 0) {
    #pragma unroll
    for (int s = 0; s < 4; ++s) {
      const float inv = 1.0f / l_lane[s];
      const int q = s * 16 + c16;
      #pragma unroll
      for (int rr = 0; rr < 4; ++rr) {
        Yl[(g4 * 4 + rr) * 66 + q]      = acc[s][0][rr] * inv;
        Yl[(16 + g4 * 4 + rr) * 66 + q] = acc[s][1][rr] * inv;
      }
    }
  }
  __syncthreads();

  // ---- fused out-projection + residual: out = Ww @ y + bw + x ----
  const int nl = tid & 63;
  const int cg = tid >> 6;
  float oacc[8];
  #pragma unroll
  for (int i = 0; i < 8; ++i) oacc[i] = bw[cg * 8 + i];
  #pragma unroll
  for (int d = 0; d < CI; ++d) {
    const float yv = Yl[d * 66 + nl];
    #pragma unroll
    for (int i = 0; i < 8; ++i)
      oacc[i] = fmaf(WwL[(cg * 8 + i) * CI + d], yv, oacc[i]);
  }
  #pragma unroll
  for (int i = 0; i < 8; ++i) {
    const size_t idx = ((size_t)(b * C_ + cg * 8 + i)) * N_ + n0 + nl;
    out[idx] = oacc[i] + x[idx];
  }
}

extern "C" void kernel_launch(void* const* d_in, const int* in_sizes, int n_in,
                              void* d_out, int out_size, void* d_ws, size_t ws_size,
                              hipStream_t stream) {
  const float* x  = (const float*)d_in[0];
  const float* Wg = (const float*)d_in[1];
  const float* bg = (const float*)d_in[2];
  const float* Wt = (const float*)d_in[3];
  const float* bt = (const float*)d_in[4];
  const float* Wp = (const float*)d_in[5];
  const float* bp = (const float*)d_in[6];
  const float* Ww = (const float*)d_in[7];
  const float* bw = (const float*)d_in[8];
  float* out = (float*)d_out;

  char* ws = (char*)d_ws;
  ushort* theta_t = (ushort*)(ws);
  ushort* phi_t   = (ushort*)(ws + (size_t)2 * 1024 * 1024);
  ushort* gmat    = (ushort*)(ws + (size_t)4 * 1024 * 1024);

  proj_kernel<<<dim3(N_ / 64, B_, 3), 256, 0, stream>>>(
      x, Wg, bg, Wt, bt, Wp, bp, theta_t, phi_t, gmat);
  attn_kernel<<<dim3((N_ / 64) * B_), 512, 0, stream>>>(
      theta_t, phi_t, gmat, Ww, bw, x, out);
}